// Round 6
// baseline (703.647 us; speedup 1.0000x reference)
//
#include <hip/hip_runtime.h>
#include <hip/hip_bf16.h>

typedef short bf16x8 __attribute__((ext_vector_type(8)));
typedef float f32x4 __attribute__((ext_vector_type(4)));

constexpr int NN = 100000;           // nodes
constexpr int NE = 1600000;          // edges
constexpr int HH = 128;              // hidden
constexpr int NR = 8;                // relations
constexpr int NBIN = 782;            // ceil(NN/128) bins by dst>>7
constexpr int CAPB = 6144;           // max edges per bin on the LDS fast path

__device__ __forceinline__ unsigned short f2bf(float f) {
    unsigned b = __float_as_uint(f);
    b += 0x7fffu + ((b >> 16) & 1u);       // round-to-nearest-even
    return (unsigned short)(b >> 16);
}

// ---- W convert + transpose: Wt[L][s][f][d] (bf16) from fp32 W[d][f] ----
__global__ void convertW(const float* __restrict__ Wr0, const float* __restrict__ Wq0,
                         const float* __restrict__ Wr1, const float* __restrict__ Wq1,
                         unsigned short* __restrict__ Wt) {
    int o = blockIdx.x * blockDim.x + threadIdx.x;
    if (o >= 2 * 9 * 128 * 128) return;
    int L = o / 147456;
    int rem = o - L * 147456;
    int s = rem >> 14;
    int p = rem & 16383;
    int f = p >> 7;
    int d = p & 127;
    const float* Wq = L ? Wq1 : Wq0;
    const float* Wr = L ? Wr1 : Wr0;
    float v = (s == 0) ? Wq[d * 128 + f] : Wr[((s - 1) * 128 + d) * 128 + f];
    Wt[o] = f2bf(v);
}

// ---- x -> bf16 pairs: xb32[n][l] = pack(x[n][2l], x[n][2l+1]) ----
__global__ void convertX(const int* __restrict__ node_idx, const float* __restrict__ emb,
                         unsigned* __restrict__ xb32) {
    int i = blockIdx.x * blockDim.x + threadIdx.x;
    if (i >= NN * 64) return;
    int n = i >> 6, dp = i & 63;
    int row = node_idx[n];
    float2 v = *((const float2*)(emb + (size_t)row * HH) + dp);
    xb32[(size_t)n * 64 + dp] = (unsigned)f2bf(v.x) | ((unsigned)f2bf(v.y) << 16);
}

// ---- pass A1: per-bin edge counts (LDS histogram -> global merge) ----
__global__ __launch_bounds__(256) void binCount(const int* __restrict__ edst,
                                                unsigned* __restrict__ binCounts) {
    __shared__ unsigned hist[NBIN];
    for (int i = threadIdx.x; i < NBIN; i += 256) hist[i] = 0;
    __syncthreads();
    int stride = gridDim.x * 256;
    for (int e = blockIdx.x * 256 + threadIdx.x; e < NE; e += stride)
        atomicAdd(&hist[((unsigned)edst[e]) >> 7], 1u);
    __syncthreads();
    for (int i = threadIdx.x; i < NBIN; i += 256)
        if (hist[i]) atomicAdd(&binCounts[i], hist[i]);
}

// ---- pass A2: exclusive scan of 782 bin counts; init cursors ----
__global__ void binScan(const unsigned* __restrict__ binCounts,
                        unsigned* __restrict__ binStarts,
                        unsigned* __restrict__ binCursor) {
    __shared__ unsigned sh[1024];
    int tid = threadIdx.x;
    unsigned v = (tid < NBIN) ? binCounts[tid] : 0u;
    sh[tid] = v;
    __syncthreads();
    for (int ofs = 1; ofs < 1024; ofs <<= 1) {
        unsigned t = (tid >= ofs) ? sh[tid - ofs] : 0u;
        __syncthreads();
        sh[tid] += t;
        __syncthreads();
    }
    if (tid < NBIN) {
        unsigned s = sh[tid] - v;
        binStarts[tid] = s;
        binCursor[tid] = s;
    }
    if (tid == 0) binStarts[NBIN] = NE;
}

// ---- pass A3: scatter edges into bins (block-chunked -> L2-local writes) ----
// payload: src(17b) | rel(3b)<<17 | dstlow(7b)<<20
__global__ __launch_bounds__(256) void binScatter(
        const int* __restrict__ esrc, const int* __restrict__ edst,
        const int* __restrict__ etype, unsigned* __restrict__ binCursor,
        unsigned* __restrict__ binned) {
    __shared__ unsigned hist[NBIN];
    __shared__ unsigned cur[NBIN];
    for (int i = threadIdx.x; i < NBIN; i += 256) hist[i] = 0;
    __syncthreads();
    int per = (NE + gridDim.x - 1) / gridDim.x;
    int lo = blockIdx.x * per;
    int hi = lo + per; if (hi > NE) hi = NE;
    for (int e = lo + threadIdx.x; e < hi; e += 256)
        atomicAdd(&hist[((unsigned)edst[e]) >> 7], 1u);
    __syncthreads();
    for (int i = threadIdx.x; i < NBIN; i += 256) {
        unsigned c = hist[i];
        cur[i] = c ? atomicAdd(&binCursor[i], c) : 0u;
    }
    __syncthreads();
    for (int e = lo + threadIdx.x; e < hi; e += 256) {
        unsigned d = (unsigned)edst[e];
        unsigned b = d >> 7;
        unsigned pos = atomicAdd(&cur[b], 1u);
        binned[pos] = (unsigned)esrc[e] | (((unsigned)etype[e]) << 17) |
                      ((d & 127u) << 20);
    }
}

// ---- pass B: per-bin LDS sort by (dstlow,rel); emit sorted epk + CSR starts ----
__global__ __launch_bounds__(256) void binSort(
        const unsigned* __restrict__ binStarts, const unsigned* __restrict__ binned,
        unsigned* __restrict__ epk, unsigned* __restrict__ starts) {
    __shared__ unsigned hist[1024];
    __shared__ unsigned scn[1024];
    __shared__ unsigned part[256];
    __shared__ unsigned buf[CAPB];
    __shared__ unsigned outb[CAPB];
    int bin = blockIdx.x;
    int tid = threadIdx.x;
    unsigned base = binStarts[bin];
    int cnt = (int)(binStarts[bin + 1] - base);

    for (int i = tid; i < 1024; i += 256) hist[i] = 0;
    __syncthreads();
    for (int i = tid; i < cnt; i += 256) {
        unsigned p = binned[base + i];
        if (i < CAPB) buf[i] = p;
        atomicAdd(&hist[(p >> 17) & 0x3ffu], 1u);   // key = dstlow*8 + rel
    }
    __syncthreads();
    // exclusive scan of hist[1024]
    unsigned h4[4], tsum = 0;
#pragma unroll
    for (int j = 0; j < 4; ++j) { h4[j] = hist[tid * 4 + j]; tsum += h4[j]; }
    part[tid] = tsum;
    __syncthreads();
    for (int ofs = 1; ofs < 256; ofs <<= 1) {
        unsigned t = (tid >= ofs) ? part[tid - ofs] : 0u;
        __syncthreads();
        part[tid] += t;
        __syncthreads();
    }
    unsigned run = part[tid] - tsum;
#pragma unroll
    for (int j = 0; j < 4; ++j) { scn[tid * 4 + j] = run; run += h4[j]; }
    __syncthreads();
    // global CSR starts (coalesced; starts[node*8+rel] == base + scn[key])
    for (int i = tid; i < 1024; i += 256) {
        starts[(size_t)bin * 1024 + i] = base + scn[i];
        hist[i] = scn[i];                            // reuse hist as cursor
    }
    __syncthreads();
    if (cnt <= CAPB) {
        for (int i = tid; i < cnt; i += 256) {
            unsigned p = buf[i];
            unsigned pos = atomicAdd(&hist[(p >> 17) & 0x3ffu], 1u);
            outb[pos] = p;
        }
        __syncthreads();
        for (int i = tid; i < cnt; i += 256) epk[base + i] = outb[i];
    } else {                                          // never expected; safety
        for (int i = tid; i < cnt; i += 256) {
            unsigned p = binned[base + i];
            unsigned pos = atomicAdd(&hist[(p >> 17) & 0x3ffu], 1u);
            epk[base + pos] = p;
        }
    }
}

// ---- gather+mean: one wave per dst node, 8-deep load ILP, rel from payload ----
__global__ __launch_bounds__(256) void gatherNode(
        const unsigned* __restrict__ starts, const unsigned* __restrict__ epk,
        const unsigned* __restrict__ xb32, unsigned* __restrict__ h32) {
    int node = blockIdx.x * 4 + (threadIdx.x >> 6);
    if (node >= NN) return;
    int lane = threadIdx.x & 63;

    unsigned bv = 0;
    if (lane < 9) bv = starts[(size_t)node * 8 + lane];
    unsigned b[9];
#pragma unroll
    for (int r = 0; r < 9; ++r) b[r] = __shfl(bv, r);
    unsigned s0 = b[0], s1 = b[8];
    int cnt = (int)__builtin_amdgcn_readfirstlane((int)(s1 - s0));

    float a[8][2];
#pragma unroll
    for (int r = 0; r < 8; ++r) { a[r][0] = 0.f; a[r][1] = 0.f; }

    for (int c0 = 0; c0 < cnt; c0 += 64) {
        unsigned myE = s0 + (unsigned)c0 + (unsigned)lane;
        unsigned pk = (myE < s1) ? epk[myE] : 0u;
        int cend = cnt - c0;
        if (cend > 64) cend = 64;
        for (int base = 0; base < cend; base += 8) {
            int m = cend - base;
            if (m > 8) m = 8;
            unsigned pj[8], qj[8];
#pragma unroll
            for (int j = 0; j < 8; ++j)
                pj[j] = (j < m) ? (unsigned)__shfl((int)pk, base + j) : 0u;
#pragma unroll
            for (int j = 0; j < 8; ++j)
                if (j < m) qj[j] = xb32[(size_t)(pj[j] & 0x1ffffu) * 64 + lane];
#pragma unroll
            for (int j = 0; j < 8; ++j) {
                if (j < m) {
                    float lo = __uint_as_float(qj[j] << 16);
                    float hi = __uint_as_float(qj[j] & 0xffff0000u);
                    switch (__builtin_amdgcn_readfirstlane(
                                (int)((pj[j] >> 17) & 7u))) {
                        case 0: a[0][0] += lo; a[0][1] += hi; break;
                        case 1: a[1][0] += lo; a[1][1] += hi; break;
                        case 2: a[2][0] += lo; a[2][1] += hi; break;
                        case 3: a[3][0] += lo; a[3][1] += hi; break;
                        case 4: a[4][0] += lo; a[4][1] += hi; break;
                        case 5: a[5][0] += lo; a[5][1] += hi; break;
                        case 6: a[6][0] += lo; a[6][1] += hi; break;
                        default: a[7][0] += lo; a[7][1] += hi; break;
                    }
                }
            }
        }
    }

#pragma unroll
    for (int r = 0; r < 8; ++r) {
        unsigned c = b[r + 1] - b[r];
        float inv = (c > 1u) ? (1.f / (float)c) : 1.f;
        unsigned out = (unsigned)f2bf(a[r][0] * inv) |
                       ((unsigned)f2bf(a[r][1] * inv) << 16);
        h32[((size_t)node * 8 + r) * 64 + lane] = out;
    }
}

// ---- fused layer GEMM: out[M,128] = relu([x|h0..h7] @ Wt^T + b) ----
// NOTE: x and outB may alias (layer 0 writes in place: each block reads x only
// for its own 64 rows at s=0, before its epilogue writes them) -> no restrict.
__global__ __launch_bounds__(256) void rgcnGemm(const unsigned short* x,
                                                const unsigned short* __restrict__ h,
                                                const unsigned short* __restrict__ Wt,
                                                const float* __restrict__ bias,
                                                float* __restrict__ outF,
                                                unsigned short* outB) {
    constexpr int LDA = 136;   // +8 bf16 pad
    __shared__ __align__(16) unsigned short A_lds[64 * LDA];
    __shared__ __align__(16) unsigned short B_lds[128 * LDA];

    int tid = threadIdx.x;
    int wid = tid >> 6, lane = tid & 63;
    int quad = lane >> 4, l16 = lane & 15;
    int wr = wid >> 1, wc = wid & 1;
    int m0 = blockIdx.x * 64;
    int chunk = tid & 15, rip = tid >> 4;

    f32x4 acc[2][4];
#pragma unroll
    for (int st = 0; st < 2; ++st)
#pragma unroll
        for (int nt = 0; nt < 4; ++nt) acc[st][nt] = (f32x4){0.f, 0.f, 0.f, 0.f};

    for (int s = 0; s < 9; ++s) {
        __syncthreads();
#pragma unroll
        for (int p = 0; p < 4; ++p) {
            int r = p * 16 + rip;
            int node = m0 + r;
            node = node < NN ? node : NN - 1;
            const unsigned short* rp = (s == 0)
                ? (x + (size_t)node * HH)
                : (h + ((size_t)node * 8 + (s - 1)) * HH);
            uint4 v = *((const uint4*)rp + chunk);
            *(uint4*)(&A_lds[r * LDA + chunk * 8]) = v;
        }
        const unsigned short* Bbase = Wt + s * 16384;
#pragma unroll
        for (int p = 0; p < 8; ++p) {
            int r = p * 16 + rip;
            uint4 v = *((const uint4*)(Bbase + r * 128) + chunk);
            *(uint4*)(&B_lds[r * LDA + chunk * 8]) = v;
        }
        __syncthreads();
#pragma unroll
        for (int kt = 0; kt < 4; ++kt) {
            int ko = kt * 32 + quad * 8;
            bf16x8 a[2], b[4];
            a[0] = *(const bf16x8*)(&A_lds[(wr * 32 + l16) * LDA + ko]);
            a[1] = *(const bf16x8*)(&A_lds[(wr * 32 + 16 + l16) * LDA + ko]);
#pragma unroll
            for (int nt = 0; nt < 4; ++nt)
                b[nt] = *(const bf16x8*)(&B_lds[(wc * 64 + nt * 16 + l16) * LDA + ko]);
#pragma unroll
            for (int st = 0; st < 2; ++st)
#pragma unroll
                for (int nt = 0; nt < 4; ++nt)
                    acc[st][nt] = __builtin_amdgcn_mfma_f32_16x16x32_bf16(
                        a[st], b[nt], acc[st][nt], 0, 0, 0);
        }
    }
#pragma unroll
    for (int st = 0; st < 2; ++st) {
        int rowbase = m0 + wr * 32 + st * 16 + quad * 4;
#pragma unroll
        for (int nt = 0; nt < 4; ++nt) {
            int n = wc * 64 + nt * 16 + l16;
            float bv = bias[n];
#pragma unroll
            for (int rg = 0; rg < 4; ++rg) {
                int node = rowbase + rg;
                if (node < NN) {
                    float v = acc[st][nt][rg] + bv;
                    v = v > 0.f ? v : 0.f;
                    if (outF) outF[(size_t)node * HH + n] = v;
                    else outB[(size_t)node * HH + n] = f2bf(v);
                }
            }
        }
    }
}

extern "C" void kernel_launch(void* const* d_in, const int* in_sizes, int n_in,
                              void* d_out, int out_size, void* d_ws, size_t ws_size,
                              hipStream_t stream) {
    const int* node_idx = (const int*)d_in[0];
    const int* eidx     = (const int*)d_in[1];
    const int* etype    = (const int*)d_in[2];
    const float* emb    = (const float*)d_in[3];
    const float* Wr0    = (const float*)d_in[4];
    const float* Wq0    = (const float*)d_in[5];
    const float* b0     = (const float*)d_in[6];
    const float* Wr1    = (const float*)d_in[7];
    const float* Wq1    = (const float*)d_in[8];
    const float* b1     = (const float*)d_in[9];
    const int* esrc = eidx;
    const int* edst = eidx + NE;

    char* ws = (char*)d_ws;
    size_t off = 0;
    auto alloc = [&](size_t bytes) -> void* {
        void* p = ws + off;
        off = (off + bytes + 255) & ~(size_t)255;
        return p;
    };
    // Workspace ~240.6 MB (under round-1's proven-good 247 MB).
    unsigned* binCounts = (unsigned*)alloc((size_t)NBIN * 4);
    unsigned* binStarts = (unsigned*)alloc((size_t)(NBIN + 1) * 4);
    unsigned* binCursor = (unsigned*)alloc((size_t)NBIN * 4);
    unsigned* starts    = (unsigned*)alloc((size_t)NBIN * 1024 * 4);   // 3.2 MB CSR
    unsigned* epk       = (unsigned*)alloc((size_t)NE * 4);
    unsigned* xb32      = (unsigned*)alloc((size_t)NN * 64 * 4);
    unsigned* h32       = (unsigned*)alloc((size_t)NN * 8 * 64 * 4);   // 204.8 MB
    unsigned short* Wt  = (unsigned short*)alloc((size_t)2 * 9 * 16384 * 2);
    unsigned* binned = h32;   // alias: h32 dead until gatherNode, binned dead after binSort
    (void)ws_size; (void)n_in; (void)in_sizes; (void)out_size;

    hipMemsetAsync(binCounts, 0, (size_t)NBIN * 4, stream);
    convertW<<<(2 * 9 * 16384 + 255) / 256, 256, 0, stream>>>(Wr0, Wq0, Wr1, Wq1, Wt);
    convertX<<<(NN * 64 + 255) / 256, 256, 0, stream>>>(node_idx, emb, xb32);
    binCount<<<256, 256, 0, stream>>>(edst, binCounts);
    binScan<<<1, 1024, 0, stream>>>(binCounts, binStarts, binCursor);
    binScatter<<<128, 256, 0, stream>>>(esrc, edst, etype, binCursor, binned);
    binSort<<<NBIN, 256, 0, stream>>>(binStarts, binned, epk, starts);

    int nblk = (NN + 63) / 64;
    // layer 0: gather on x, GEMM -> relu -> bf16 pairs written in place into xb32
    gatherNode<<<(NN + 3) / 4, 256, 0, stream>>>(starts, epk, xb32, h32);
    rgcnGemm<<<nblk, 256, 0, stream>>>((const unsigned short*)xb32,
                                       (const unsigned short*)h32, Wt, b0,
                                       nullptr, (unsigned short*)xb32);
    // layer 1: gather on relu(out0), GEMM -> relu -> fp32 d_out
    gatherNode<<<(NN + 3) / 4, 256, 0, stream>>>(starts, epk, xb32, h32);
    rgcnGemm<<<nblk, 256, 0, stream>>>((const unsigned short*)xb32,
                                       (const unsigned short*)h32, Wt + 147456, b1,
                                       (float*)d_out, nullptr);
}

// Round 7
// 602.519 us; speedup vs baseline: 1.1678x; 1.1678x over previous
//
#include <hip/hip_runtime.h>
#include <hip/hip_bf16.h>

typedef short bf16x8 __attribute__((ext_vector_type(8)));
typedef float f32x4 __attribute__((ext_vector_type(4)));

constexpr int NN = 100000;           // nodes
constexpr int NE = 1600000;          // edges
constexpr int HH = 128;              // hidden
constexpr int NR = 8;                // relations
constexpr int NBIN = 782;            // ceil(NN/128) bins by dst>>7
constexpr int CAPB = 6144;           // max edges per bin on the LDS fast path

__device__ __forceinline__ unsigned short f2bf(float f) {
    unsigned b = __float_as_uint(f);
    b += 0x7fffu + ((b >> 16) & 1u);       // round-to-nearest-even
    return (unsigned short)(b >> 16);
}

// ---- fused convert: blocks [0,144): W transpose; blocks [144, 144+25000): x ----
// Wt[L][s][f][d] (bf16) from fp32 W[d][f]; xb32[n][l] = pack(x[n][2l], x[n][2l+1])
__global__ void convertWX(const float* __restrict__ Wr0, const float* __restrict__ Wq0,
                          const float* __restrict__ Wr1, const float* __restrict__ Wq1,
                          unsigned short* __restrict__ Wt,
                          const int* __restrict__ node_idx,
                          const float* __restrict__ emb,
                          unsigned* __restrict__ xb32) {
    if (blockIdx.x < 1152) {           // 1152*256 = 294912 = 2*9*128*128
        int o = blockIdx.x * 256 + threadIdx.x;
        int L = o / 147456;
        int rem = o - L * 147456;
        int s = rem >> 14;
        int p = rem & 16383;
        int f = p >> 7;
        int d = p & 127;
        const float* Wq = L ? Wq1 : Wq0;
        const float* Wr = L ? Wr1 : Wr0;
        float v = (s == 0) ? Wq[d * 128 + f] : Wr[((s - 1) * 128 + d) * 128 + f];
        Wt[o] = f2bf(v);
    } else {
        int i = (blockIdx.x - 1152) * 256 + threadIdx.x;
        if (i >= NN * 64) return;
        int n = i >> 6, dp = i & 63;
        int row = node_idx[n];
        float2 v = *((const float2*)(emb + (size_t)row * HH) + dp);
        xb32[(size_t)n * 64 + dp] = (unsigned)f2bf(v.x) | ((unsigned)f2bf(v.y) << 16);
    }
}

// ---- pass A1: per-bin edge counts (LDS histogram -> global merge) ----
__global__ __launch_bounds__(256) void binCount(const int* __restrict__ edst,
                                                unsigned* __restrict__ binCounts) {
    __shared__ unsigned hist[NBIN];
    for (int i = threadIdx.x; i < NBIN; i += 256) hist[i] = 0;
    __syncthreads();
    int stride = gridDim.x * 256;
    for (int e = blockIdx.x * 256 + threadIdx.x; e < NE; e += stride)
        atomicAdd(&hist[((unsigned)edst[e]) >> 7], 1u);
    __syncthreads();
    for (int i = threadIdx.x; i < NBIN; i += 256)
        if (hist[i]) atomicAdd(&binCounts[i], hist[i]);
}

// ---- pass A2: exclusive scan of 782 bin counts; init cursors ----
__global__ void binScan(const unsigned* __restrict__ binCounts,
                        unsigned* __restrict__ binStarts,
                        unsigned* __restrict__ binCursor) {
    __shared__ unsigned sh[1024];
    int tid = threadIdx.x;
    unsigned v = (tid < NBIN) ? binCounts[tid] : 0u;
    sh[tid] = v;
    __syncthreads();
    for (int ofs = 1; ofs < 1024; ofs <<= 1) {
        unsigned t = (tid >= ofs) ? sh[tid - ofs] : 0u;
        __syncthreads();
        sh[tid] += t;
        __syncthreads();
    }
    if (tid < NBIN) {
        unsigned s = sh[tid] - v;
        binStarts[tid] = s;
        binCursor[tid] = s;
    }
    if (tid == 0) binStarts[NBIN] = NE;
}

// ---- pass A3: scatter edges into bins (block-chunked -> L2-local writes) ----
// payload: src(17b) | rel(3b)<<17 | dstlow(7b)<<20
__global__ __launch_bounds__(256) void binScatter(
        const int* __restrict__ esrc, const int* __restrict__ edst,
        const int* __restrict__ etype, unsigned* __restrict__ binCursor,
        unsigned* __restrict__ binned) {
    __shared__ unsigned hist[NBIN];
    __shared__ unsigned cur[NBIN];
    for (int i = threadIdx.x; i < NBIN; i += 256) hist[i] = 0;
    __syncthreads();
    int per = (NE + gridDim.x - 1) / gridDim.x;
    int lo = blockIdx.x * per;
    int hi = lo + per; if (hi > NE) hi = NE;
    for (int e = lo + threadIdx.x; e < hi; e += 256)
        atomicAdd(&hist[((unsigned)edst[e]) >> 7], 1u);
    __syncthreads();
    for (int i = threadIdx.x; i < NBIN; i += 256) {
        unsigned c = hist[i];
        cur[i] = c ? atomicAdd(&binCursor[i], c) : 0u;
    }
    __syncthreads();
    for (int e = lo + threadIdx.x; e < hi; e += 256) {
        unsigned d = (unsigned)edst[e];
        unsigned b = d >> 7;
        unsigned pos = atomicAdd(&cur[b], 1u);
        binned[pos] = (unsigned)esrc[e] | (((unsigned)etype[e]) << 17) |
                      ((d & 127u) << 20);
    }
}

// ---- pass B: per-bin LDS sort by (dstlow,rel); emit src-only epk + CSR starts ----
__global__ __launch_bounds__(256) void binSort(
        const unsigned* __restrict__ binStarts, const unsigned* __restrict__ binned,
        unsigned* __restrict__ epk, unsigned* __restrict__ starts) {
    __shared__ unsigned hist[1024];
    __shared__ unsigned scn[1024];
    __shared__ unsigned part[256];
    __shared__ unsigned buf[CAPB];
    __shared__ unsigned outb[CAPB];
    int bin = blockIdx.x;
    int tid = threadIdx.x;
    unsigned base = binStarts[bin];
    int cnt = (int)(binStarts[bin + 1] - base);

    for (int i = tid; i < 1024; i += 256) hist[i] = 0;
    __syncthreads();
    for (int i = tid; i < cnt; i += 256) {
        unsigned p = binned[base + i];
        if (i < CAPB) buf[i] = p;
        atomicAdd(&hist[(p >> 17) & 0x3ffu], 1u);   // key = dstlow*8 + rel
    }
    __syncthreads();
    // exclusive scan of hist[1024]
    unsigned h4[4], tsum = 0;
#pragma unroll
    for (int j = 0; j < 4; ++j) { h4[j] = hist[tid * 4 + j]; tsum += h4[j]; }
    part[tid] = tsum;
    __syncthreads();
    for (int ofs = 1; ofs < 256; ofs <<= 1) {
        unsigned t = (tid >= ofs) ? part[tid - ofs] : 0u;
        __syncthreads();
        part[tid] += t;
        __syncthreads();
    }
    unsigned run = part[tid] - tsum;
#pragma unroll
    for (int j = 0; j < 4; ++j) { scn[tid * 4 + j] = run; run += h4[j]; }
    __syncthreads();
    // global CSR starts (coalesced; starts[node*8+rel] == base + scn[key])
    for (int i = tid; i < 1024; i += 256) {
        starts[(size_t)bin * 1024 + i] = base + scn[i];
        hist[i] = scn[i];                            // reuse hist as cursor
    }
    __syncthreads();
    if (cnt <= CAPB) {
        for (int i = tid; i < cnt; i += 256) {
            unsigned p = buf[i];
            unsigned pos = atomicAdd(&hist[(p >> 17) & 0x3ffu], 1u);
            outb[pos] = p & 0x1ffffu;                // src only (R5-compatible)
        }
        __syncthreads();
        for (int i = tid; i < cnt; i += 256) epk[base + i] = outb[i];
    } else {                                          // never expected; safety
        for (int i = tid; i < cnt; i += 256) {
            unsigned p = binned[base + i];
            unsigned pos = atomicAdd(&hist[(p >> 17) & 0x3ffu], 1u);
            epk[base + pos] = p & 0x1ffffu;
        }
    }
}

// ---- gather+mean: ONE WAVE PER DST NODE, all 8 relations, 8-deep load ILP ----
// (R5-proven codegen: 40 VGPR, ~100% VALUBusy, 135 us)
// xb32: [NN][64] bf16-pair dwords.  h32: [NN][8][64] node-major output.
__global__ __launch_bounds__(256) void gatherNode(
        const unsigned* __restrict__ starts, const unsigned* __restrict__ epk,
        const unsigned* __restrict__ xb32, unsigned* __restrict__ h32) {
    int node = blockIdx.x * 4 + (threadIdx.x >> 6);
    if (node >= NN) return;
    int lane = threadIdx.x & 63;

    // 9 CSR boundaries for this node's 8 relation buckets
    unsigned bv = 0;
    if (lane < 9) bv = starts[(size_t)node * 8 + lane];
    unsigned b[9];
#pragma unroll
    for (int r = 0; r < 9; ++r) b[r] = __shfl(bv, r);
    unsigned s0 = b[0], s1 = b[8];
    int cnt = (int)__builtin_amdgcn_readfirstlane((int)(s1 - s0));

    float a[8][2];
#pragma unroll
    for (int r = 0; r < 8; ++r) { a[r][0] = 0.f; a[r][1] = 0.f; }

    for (int c0 = 0; c0 < cnt; c0 += 64) {
        unsigned myE = s0 + (unsigned)c0 + (unsigned)lane;
        unsigned pk = (myE < s1) ? epk[myE] : 0u;
        // per-lane relation id of its edge (edges are rel-sorted in segment)
        unsigned rl = 0;
#pragma unroll
        for (int r = 1; r < 8; ++r) rl += (myE >= b[r]) ? 1u : 0u;
        pk |= rl << 24;
        int cend = cnt - c0;
        if (cend > 64) cend = 64;
        for (int base = 0; base < cend; base += 8) {
            int m = cend - base;
            if (m > 8) m = 8;
            unsigned pj[8], qj[8];
#pragma unroll
            for (int j = 0; j < 8; ++j)
                pj[j] = (j < m) ? (unsigned)__shfl((int)pk, base + j) : 0u;
#pragma unroll
            for (int j = 0; j < 8; ++j)
                if (j < m) qj[j] = xb32[(size_t)(pj[j] & 0x1ffffu) * 64 + lane];
#pragma unroll
            for (int j = 0; j < 8; ++j) {
                if (j < m) {
                    float lo = __uint_as_float(qj[j] << 16);
                    float hi = __uint_as_float(qj[j] & 0xffff0000u);
                    switch (__builtin_amdgcn_readfirstlane((int)(pj[j] >> 24))) {
                        case 0: a[0][0] += lo; a[0][1] += hi; break;
                        case 1: a[1][0] += lo; a[1][1] += hi; break;
                        case 2: a[2][0] += lo; a[2][1] += hi; break;
                        case 3: a[3][0] += lo; a[3][1] += hi; break;
                        case 4: a[4][0] += lo; a[4][1] += hi; break;
                        case 5: a[5][0] += lo; a[5][1] += hi; break;
                        case 6: a[6][0] += lo; a[6][1] += hi; break;
                        default: a[7][0] += lo; a[7][1] += hi; break;
                    }
                }
            }
        }
    }

    // mean-normalize and store 8 contiguous rows (2 KB per node)
#pragma unroll
    for (int r = 0; r < 8; ++r) {
        unsigned c = b[r + 1] - b[r];
        float inv = (c > 1u) ? (1.f / (float)c) : 1.f;
        unsigned out = (unsigned)f2bf(a[r][0] * inv) |
                       ((unsigned)f2bf(a[r][1] * inv) << 16);
        h32[((size_t)node * 8 + r) * 64 + lane] = out;
    }
}

// ---- fused layer GEMM: out[M,128] = relu([x|h0..h7] @ Wt^T + b) ----
// NOTE: x and outB may alias (layer 0 writes in place: each block reads x only
// for its own 64 rows at s=0, before its epilogue writes them) -> no restrict.
__global__ __launch_bounds__(256) void rgcnGemm(const unsigned short* x,
                                                const unsigned short* __restrict__ h,
                                                const unsigned short* __restrict__ Wt,
                                                const float* __restrict__ bias,
                                                float* __restrict__ outF,
                                                unsigned short* outB) {
    constexpr int LDA = 136;   // +8 bf16 pad
    __shared__ __align__(16) unsigned short A_lds[64 * LDA];
    __shared__ __align__(16) unsigned short B_lds[128 * LDA];

    int tid = threadIdx.x;
    int wid = tid >> 6, lane = tid & 63;
    int quad = lane >> 4, l16 = lane & 15;
    int wr = wid >> 1, wc = wid & 1;
    int m0 = blockIdx.x * 64;
    int chunk = tid & 15, rip = tid >> 4;

    f32x4 acc[2][4];
#pragma unroll
    for (int st = 0; st < 2; ++st)
#pragma unroll
        for (int nt = 0; nt < 4; ++nt) acc[st][nt] = (f32x4){0.f, 0.f, 0.f, 0.f};

    for (int s = 0; s < 9; ++s) {
        __syncthreads();
#pragma unroll
        for (int p = 0; p < 4; ++p) {
            int r = p * 16 + rip;
            int node = m0 + r;
            node = node < NN ? node : NN - 1;
            const unsigned short* rp = (s == 0)
                ? (x + (size_t)node * HH)
                : (h + ((size_t)node * 8 + (s - 1)) * HH);
            uint4 v = *((const uint4*)rp + chunk);
            *(uint4*)(&A_lds[r * LDA + chunk * 8]) = v;
        }
        const unsigned short* Bbase = Wt + s * 16384;
#pragma unroll
        for (int p = 0; p < 8; ++p) {
            int r = p * 16 + rip;
            uint4 v = *((const uint4*)(Bbase + r * 128) + chunk);
            *(uint4*)(&B_lds[r * LDA + chunk * 8]) = v;
        }
        __syncthreads();
#pragma unroll
        for (int kt = 0; kt < 4; ++kt) {
            int ko = kt * 32 + quad * 8;
            bf16x8 a[2], b[4];
            a[0] = *(const bf16x8*)(&A_lds[(wr * 32 + l16) * LDA + ko]);
            a[1] = *(const bf16x8*)(&A_lds[(wr * 32 + 16 + l16) * LDA + ko]);
#pragma unroll
            for (int nt = 0; nt < 4; ++nt)
                b[nt] = *(const bf16x8*)(&B_lds[(wc * 64 + nt * 16 + l16) * LDA + ko]);
#pragma unroll
            for (int st = 0; st < 2; ++st)
#pragma unroll
                for (int nt = 0; nt < 4; ++nt)
                    acc[st][nt] = __builtin_amdgcn_mfma_f32_16x16x32_bf16(
                        a[st], b[nt], acc[st][nt], 0, 0, 0);
        }
    }
#pragma unroll
    for (int st = 0; st < 2; ++st) {
        int rowbase = m0 + wr * 32 + st * 16 + quad * 4;
#pragma unroll
        for (int nt = 0; nt < 4; ++nt) {
            int n = wc * 64 + nt * 16 + l16;
            float bv = bias[n];
#pragma unroll
            for (int rg = 0; rg < 4; ++rg) {
                int node = rowbase + rg;
                if (node < NN) {
                    float v = acc[st][nt][rg] + bv;
                    v = v > 0.f ? v : 0.f;
                    if (outF) outF[(size_t)node * HH + n] = v;
                    else outB[(size_t)node * HH + n] = f2bf(v);
                }
            }
        }
    }
}

extern "C" void kernel_launch(void* const* d_in, const int* in_sizes, int n_in,
                              void* d_out, int out_size, void* d_ws, size_t ws_size,
                              hipStream_t stream) {
    const int* node_idx = (const int*)d_in[0];
    const int* eidx     = (const int*)d_in[1];
    const int* etype    = (const int*)d_in[2];
    const float* emb    = (const float*)d_in[3];
    const float* Wr0    = (const float*)d_in[4];
    const float* Wq0    = (const float*)d_in[5];
    const float* b0     = (const float*)d_in[6];
    const float* Wr1    = (const float*)d_in[7];
    const float* Wq1    = (const float*)d_in[8];
    const float* b1     = (const float*)d_in[9];
    const int* esrc = eidx;
    const int* edst = eidx + NE;

    char* ws = (char*)d_ws;
    size_t off = 0;
    auto alloc = [&](size_t bytes) -> void* {
        void* p = ws + off;
        off = (off + bytes + 255) & ~(size_t)255;
        return p;
    };
    // Workspace ~240.6 MB (under round-1's proven-good 247 MB).
    unsigned* binCounts = (unsigned*)alloc((size_t)NBIN * 4);
    unsigned* binStarts = (unsigned*)alloc((size_t)(NBIN + 1) * 4);
    unsigned* binCursor = (unsigned*)alloc((size_t)NBIN * 4);
    unsigned* starts    = (unsigned*)alloc((size_t)NBIN * 1024 * 4);   // 3.2 MB CSR
    unsigned* epk       = (unsigned*)alloc((size_t)NE * 4);
    unsigned* xb32      = (unsigned*)alloc((size_t)NN * 64 * 4);
    unsigned* h32       = (unsigned*)alloc((size_t)NN * 8 * 64 * 4);   // 204.8 MB
    unsigned short* Wt  = (unsigned short*)alloc((size_t)2 * 9 * 16384 * 2);
    unsigned* binned = h32;   // alias: h32 dead until gatherNode, binned dead after binSort
    (void)ws_size; (void)n_in; (void)in_sizes; (void)out_size;

    hipMemsetAsync(binCounts, 0, (size_t)NBIN * 4, stream);
    convertWX<<<1152 + (NN * 64 + 255) / 256, 256, 0, stream>>>(
        Wr0, Wq0, Wr1, Wq1, Wt, node_idx, emb, xb32);
    binCount<<<256, 256, 0, stream>>>(edst, binCounts);
    binScan<<<1, 1024, 0, stream>>>(binCounts, binStarts, binCursor);
    binScatter<<<128, 256, 0, stream>>>(esrc, edst, etype, binCursor, binned);
    binSort<<<NBIN, 256, 0, stream>>>(binStarts, binned, epk, starts);

    int nblk = (NN + 63) / 64;
    // layer 0: gather on x, GEMM -> relu -> bf16 pairs written in place into xb32
    gatherNode<<<(NN + 3) / 4, 256, 0, stream>>>(starts, epk, xb32, h32);
    rgcnGemm<<<nblk, 256, 0, stream>>>((const unsigned short*)xb32,
                                       (const unsigned short*)h32, Wt, b0,
                                       nullptr, (unsigned short*)xb32);
    // layer 1: gather on relu(out0), GEMM -> relu -> fp32 d_out
    gatherNode<<<(NN + 3) / 4, 256, 0, stream>>>(starts, epk, xb32, h32);
    rgcnGemm<<<nblk, 256, 0, stream>>>((const unsigned short*)xb32,
                                       (const unsigned short*)h32, Wt + 147456, b1,
                                       (float*)d_out, nullptr);
}